// Round 15
// baseline (75.464 us; speedup 1.0000x reference)
//
#include <hip/hip_runtime.h>

#define BN 4
#define C 256
#define H 64
#define W 64
#define CM 64
#define G 16
#define GC 16
#define KS 7
#define K2 49
#define PADD 3
#define EPSV 1e-5f

// tile = 16 wide x 8 tall (128 px); 32 tiles per (b,g)
#define WSTRIDE 132     // wgt row stride in u32 (128 + 4 pad)
#define XPW 72          // padded x row width (4 zero | 64 | 4 zero)

// workspace layout (float offsets)
#define W1T_OFF 0                       // [256][64] w1T[c][o]
#define B2P_OFF (W1T_OFF + C*CM)        // [16][64] padded bias
#define S1_OFF  (B2P_OFF + G*64)
#define B1_OFF  (S1_OFF + CM)
#define S2_OFF  (B1_OFF + CM)
#define B2C_OFF (S2_OFF + C)
#define ZERO_OFF (B2C_OFF + C)          // [16] zeros
#define ABF_OFF (ZERO_OFF + 16)         // ushort: A-frags 16g*4mt*2ks*64lane*8
#define TBF_OFF (ABF_OFF + 32768)       // ushort: t bf16 [4][32tile][128pix][64o]
#define XPAD_OFF (TBF_OFF + 524288)     // f32: xpad [4][256][64][72]

typedef __attribute__((ext_vector_type(8))) short bf16x8;
typedef __attribute__((ext_vector_type(4))) float f32x4;

__device__ __forceinline__ uint f2bf_rne(float f) {
  uint u = __float_as_uint(f);
  return (u + 0x7fffu + ((u >> 16) & 1u)) >> 16;
}

// prep: weight transforms + BN folds + padded-x copy; grid 2048.
__global__ __launch_bounds__(256) void prep_kernel(
    const float* __restrict__ x,
    const float* __restrict__ w1, const float* __restrict__ w2,
    const float* __restrict__ b2,
    const float* __restrict__ g1, const float* __restrict__ be1,
    const float* __restrict__ m1, const float* __restrict__ v1,
    const float* __restrict__ g2, const float* __restrict__ be2,
    const float* __restrict__ m2, const float* __restrict__ v2,
    float* __restrict__ ws) {
  int tid = blockIdx.x * 256 + threadIdx.x;
  int nthr = gridDim.x * 256;

  // xpad [b][c][64][72]: cols 0-3 and 68-71 zero, col p -> gx = p-4
  {
    float4* xp = (float4*)(ws + XPAD_OFF);
    const int total = BN * C * H * (XPW / 4);   // 4,718,592/4 float4s
    for (int i = tid; i < total; i += nthr) {
      int p4 = i % (XPW / 4);
      int row = i / (XPW / 4);                  // (b*C + c)*H + gy
      float4 v = {0.f, 0.f, 0.f, 0.f};
      int gx0 = p4 * 4 - 4;
      if (gx0 >= 0 && gx0 < W) v = *(const float4*)(x + (size_t)row * W + gx0);
      xp[i] = v;
    }
  }

  for (int i = tid; i < CM * C; i += nthr) {
    int o = i / C, c = i - o * C;
    ws[W1T_OFF + c * CM + o] = w1[i];
  }
  // A fragments (bf16): lane l holds A[row=mt*16+(l&15)][k=ks*32+(l>>4)*8+j]
  {
    ushort* abf = (ushort*)(ws + ABF_OFF);
    for (int i = tid; i < G * 4 * 2 * 64 * 8; i += nthr) {
      int j = i & 7, lane = (i >> 3) & 63, ks = (i >> 9) & 1;
      int mt = (i >> 10) & 3, g = (i >> 12) & 15;
      int m = mt * 16 + (lane & 15);
      int o = ks * 32 + ((lane >> 4) << 3) + j;
      float v = (m < K2) ? w2[(g * K2 + m) * CM + o] : 0.f;
      abf[i] = (ushort)f2bf_rne(v);
    }
  }
  for (int i = tid; i < G * 64; i += nthr) {
    int g = i >> 6, k = i & 63;
    ws[B2P_OFF + i] = (k < K2) ? b2[g * K2 + k] : 0.f;
  }
  if (tid < CM) {
    float inv = g1[tid] * rsqrtf(v1[tid] + EPSV);
    ws[S1_OFF + tid] = inv;
    ws[B1_OFF + tid] = be1[tid] - m1[tid] * inv;
  }
  if (tid < C) {
    float inv = g2[tid] * rsqrtf(v2[tid] + EPSV);
    ws[S2_OFF + tid] = inv;
    ws[B2C_OFF + tid] = be2[tid] - m2[tid] * inv;
  }
  if (tid < 16) ws[ZERO_OFF + tid] = 0.f;
}

// t = relu(bn1(w1 @ x)) stored bf16 [b][tile32][pix128][o64]
// tile = (y>>3)*4 + (x>>4); pix = (y&7)*16 + (x&15)
__global__ __launch_bounds__(256) void t_kernel(
    const float* __restrict__ x, float* __restrict__ ws) {
  __shared__ float part[4][32][64];
  int p = threadIdx.x & 63;
  int q = __builtin_amdgcn_readfirstlane(threadIdx.x >> 6);
  int y = blockIdx.x, b = blockIdx.y, oh = blockIdx.z;
  const float* __restrict__ w1T = ws + W1T_OFF + oh * 32;

  float acc[32];
#pragma unroll
  for (int o = 0; o < 32; ++o) acc[o] = 0.f;
  const float* __restrict__ xrow = x + (((size_t)b * C + q * 64) * H + y) * W;
#pragma unroll 2
  for (int cc = 0; cc < 64; ++cc) {
    float xv = xrow[(size_t)cc * H * W + p];
    const float* __restrict__ wr = w1T + (q * 64 + cc) * CM;
#pragma unroll
    for (int o = 0; o < 32; ++o) acc[o] = fmaf(wr[o], xv, acc[o]);
  }
#pragma unroll
  for (int o = 0; o < 32; ++o) part[q][o][p] = acc[o];
  __syncthreads();

  int tile = (y >> 3) * 4 + (p >> 4);
  int pix = (y & 7) * 16 + (p & 15);
  const float* __restrict__ s1 = ws + S1_OFF + oh * 32;
  const float* __restrict__ b1 = ws + B1_OFF + oh * 32;
  float fv[8];
#pragma unroll
  for (int i = 0; i < 8; ++i) {
    int o = q * 8 + i;
    float s = part[0][o][p] + part[1][o][p] + part[2][o][p] + part[3][o][p];
    fv[i] = fmaxf(fmaf(s, s1[o], b1[o]), 0.f);
  }
  uint4 pk;
  pk.x = f2bf_rne(fv[0]) | (f2bf_rne(fv[1]) << 16);
  pk.y = f2bf_rne(fv[2]) | (f2bf_rne(fv[3]) << 16);
  pk.z = f2bf_rne(fv[4]) | (f2bf_rne(fv[5]) << 16);
  pk.w = f2bf_rne(fv[6]) | (f2bf_rne(fv[7]) << 16);
  ushort* tbf = (ushort*)(ws + TBF_OFF);
  size_t idx = (((size_t)(b * 32 + tile) * 128 + pix) * 64) + oh * 32 + q * 8;
  *(uint4*)(tbf + idx) = pk;
}

// per (b, g, 16x8 tile): MFMA wgt-GEMM -> 13.2KB LDS -> ONE barrier ->
// stencil reading x windows directly from global (L1-resident halo).
// No gload_lds, no vmcnt asm, no phases.
__global__ __launch_bounds__(256, 3) void inv_kernel(
    const float* __restrict__ ws, float* __restrict__ out) {
  __shared__ uint wgt_u[25][WSTRIDE];   // 13.2 KB [j=k/2][pix]

  int tid = threadIdx.x;
  int lane = tid & 63;
  int wv = __builtin_amdgcn_readfirstlane(tid >> 6);
  int c16 = lane & 15, q = lane >> 4;
  int tile = blockIdx.x, g = blockIdx.y, b = blockIdx.z;
  int ty = (tile >> 2) * 8, tx = (tile & 3) * 16;
  int py = tid >> 5, pq = (tid >> 3) & 3, chq = tid & 7;

  const ushort* abf = (const ushort*)(ws + ABF_OFF);
  const ushort* tbf = (const ushort*)(ws + TBF_OFF);

  // ---- fragment + bias loads ---------------------------------------------
  bf16x8 afr[4][2], bfr[2][2];
  f32x4 bias[4];
#pragma unroll
  for (int nt = 0; nt < 2; ++nt) {
    int pix = wv * 32 + nt * 16 + c16;
#pragma unroll
    for (int ks = 0; ks < 2; ++ks)
      bfr[nt][ks] = *(const bf16x8*)(
          tbf + (((size_t)(b * 32 + tile) * 128 + pix) * 64 + ks * 32 + q * 8));
  }
#pragma unroll
  for (int mt = 0; mt < 4; ++mt) {
#pragma unroll
    for (int ks = 0; ks < 2; ++ks)
      afr[mt][ks] = *(const bf16x8*)(abf + ((g * 8 + mt * 2 + ks) * 64 + lane) * 8);
    bias[mt] = *(const f32x4*)(ws + B2P_OFF + g * 64 + mt * 16 + q * 4);
  }

  // ---- MFMA GEMM + pack into wgt_u[25][132] ------------------------------
#pragma unroll
  for (int nt = 0; nt < 2; ++nt) {
    f32x4 a[4];
#pragma unroll
    for (int mt = 0; mt < 4; ++mt) a[mt] = bias[mt];
#pragma unroll
    for (int ks = 0; ks < 2; ++ks)
#pragma unroll
      for (int mt = 0; mt < 4; ++mt)
        a[mt] = __builtin_amdgcn_mfma_f32_16x16x32_bf16(afr[mt][ks], bfr[nt][ks],
                                                        a[mt], 0, 0, 0);
    int pix = wv * 32 + nt * 16 + c16;
#pragma unroll
    for (int mt = 0; mt < 4; ++mt) {
      uint lo = f2bf_rne(a[mt][0]) | (f2bf_rne(a[mt][1]) << 16);
      uint hi = f2bf_rne(a[mt][2]) | (f2bf_rne(a[mt][3]) << 16);
      int j0v = mt * 8 + q * 2;
      if (j0v < 25) wgt_u[j0v][pix] = lo;
      if (j0v + 1 < 25) wgt_u[j0v + 1][pix] = hi;
    }
  }

  __syncthreads();

  // ---- stencil: 4 px x 2 channels per thread, windows straight from L1 ---
  const float* xp = ws + XPAD_OFF;
  const float* xc0 = xp + ((size_t)((b * C + g * GC + chq) * H)) * XPW;
  const float* xc1 = xc0 + (size_t)(8 * H) * XPW;
  float sc0 = ws[S2_OFF + g * GC + chq],     bc0 = ws[B2C_OFF + g * GC + chq];
  float sc1 = ws[S2_OFF + g * GC + chq + 8], bc1 = ws[B2C_OFF + g * GC + chq + 8];

  int colbase = tx + pq * 4;   // padded col of first aligned window float4
  f32x4 acc0 = {0.f, 0.f, 0.f, 0.f}, acc1 = {0.f, 0.f, 0.f, 0.f};

#pragma unroll
  for (int di = 0; di < KS; ++di) {
    const int j0 = (di * KS) >> 1;
    uint4 wq[4];
#pragma unroll
    for (int m = 0; m < 4; ++m)
      wq[m] = *(const uint4*)&wgt_u[j0 + m][py * 16 + pq * 4];
    // unpack 28 per-pixel weights once; shared by both channels
    float wf[28];
#pragma unroll
    for (int dj = 0; dj < KS; ++dj) {
      const int k = di * KS + dj;
      const int m = (k >> 1) - j0, hf = k & 1;
#pragma unroll
      for (int i = 0; i < 4; ++i) {
        uint u = (&wq[m].x)[i];
        wf[dj * 4 + i] = __uint_as_float(hf ? (u & 0xffff0000u) : (u << 16));
      }
    }
    int gy = ty + py + di - PADD;
    if ((unsigned)gy < H) {
      const float* r0 = xc0 + (size_t)gy * XPW + colbase;
      const float* r1 = xc1 + (size_t)gy * XPW + colbase;
      f32x4 a0 = *(const f32x4*)(r0), a1 = *(const f32x4*)(r0 + 4);
      f32x4 a2 = *(const f32x4*)(r0 + 8), a3 = *(const f32x4*)(r0 + 12);
      f32x4 b0 = *(const f32x4*)(r1), b1v = *(const f32x4*)(r1 + 4);
      f32x4 b2v = *(const f32x4*)(r1 + 8), b3 = *(const f32x4*)(r1 + 12);
      float rw0[16] = {a0[0], a0[1], a0[2], a0[3], a1[0], a1[1], a1[2], a1[3],
                       a2[0], a2[1], a2[2], a2[3], a3[0], a3[1], a3[2], a3[3]};
      float rw1[16] = {b0[0], b0[1], b0[2], b0[3], b1v[0], b1v[1], b1v[2], b1v[3],
                       b2v[0], b2v[1], b2v[2], b2v[3], b3[0], b3[1], b3[2], b3[3]};
#pragma unroll
      for (int dj = 0; dj < KS; ++dj)
#pragma unroll
        for (int i = 0; i < 4; ++i) {
          // window value for px i, tap dj: padded col colbase + i + dj + 1
          acc0[i] = fmaf(rw0[i + dj + 1], wf[dj * 4 + i], acc0[i]);
          acc1[i] = fmaf(rw1[i + dj + 1], wf[dj * 4 + i], acc1[i]);
        }
    }
  }

  // ---- bn2 + relu + store ------------------------------------------------
  float4 o0, o1;
  o0.x = fmaxf(fmaf(acc0[0], sc0, bc0), 0.f);
  o0.y = fmaxf(fmaf(acc0[1], sc0, bc0), 0.f);
  o0.z = fmaxf(fmaf(acc0[2], sc0, bc0), 0.f);
  o0.w = fmaxf(fmaf(acc0[3], sc0, bc0), 0.f);
  o1.x = fmaxf(fmaf(acc1[0], sc1, bc1), 0.f);
  o1.y = fmaxf(fmaf(acc1[1], sc1, bc1), 0.f);
  o1.z = fmaxf(fmaf(acc1[2], sc1, bc1), 0.f);
  o1.w = fmaxf(fmaf(acc1[3], sc1, bc1), 0.f);
  size_t obase = (((size_t)b * C + g * GC + chq) * H + ty + py) * W + tx + pq * 4;
  *(float4*)(out + obase) = o0;
  *(float4*)(out + obase + (size_t)8 * H * W) = o1;
}

extern "C" void kernel_launch(void* const* d_in, const int* in_sizes, int n_in,
                              void* d_out, int out_size, void* d_ws, size_t ws_size,
                              hipStream_t stream) {
  const float* x   = (const float*)d_in[0];
  const float* w1  = (const float*)d_in[1];
  const float* g1  = (const float*)d_in[2];
  const float* be1 = (const float*)d_in[3];
  const float* m1  = (const float*)d_in[4];
  const float* v1  = (const float*)d_in[5];
  const float* w2  = (const float*)d_in[6];
  const float* b2  = (const float*)d_in[7];
  const float* g2  = (const float*)d_in[8];
  const float* be2 = (const float*)d_in[9];
  const float* m2  = (const float*)d_in[10];
  const float* v2  = (const float*)d_in[11];
  float* outp = (float*)d_out;
  float* ws = (float*)d_ws;

  prep_kernel<<<dim3(2048), dim3(256), 0, stream>>>(x, w1, w2, b2, g1, be1, m1, v1,
                                                    g2, be2, m2, v2, ws);
  t_kernel<<<dim3(H, BN, 2), dim3(256), 0, stream>>>(x, ws);
  inv_kernel<<<dim3(32, G, BN), dim3(256), 0, stream>>>(ws, outp);
}

// Round 16
// 67.599 us; speedup vs baseline: 1.1164x; 1.1164x over previous
//
#include <hip/hip_runtime.h>

#define BN 4
#define C 256
#define H 64
#define W 64
#define CM 64
#define G 16
#define GC 16
#define KS 7
#define K2 49
#define PADD 3
#define EPSV 1e-5f

// tile = 16 wide x 8 tall (128 px); 32 tiles per (b,g)
#define WSTRIDE 132     // wgt row stride in u32 (128 + 4 pad)
#define XPW 72          // padded x row width (4 zero | 64 | 4 zero)
#define XPH 70          // padded x rows (3 zero | 64 | 3 zero)

// workspace layout (float offsets)
#define W1T_OFF 0                       // [256][64] w1T[c][o]
#define B2P_OFF (W1T_OFF + C*CM)        // [16][64] padded bias
#define S1_OFF  (B2P_OFF + G*64)
#define B1_OFF  (S1_OFF + CM)
#define S2_OFF  (B1_OFF + CM)
#define B2C_OFF (S2_OFF + C)
#define ZERO_OFF (B2C_OFF + C)          // [16] zeros
#define ABF_OFF (ZERO_OFF + 16)         // ushort: A-frags 16g*4mt*2ks*64lane*8
#define TBF_OFF (ABF_OFF + 32768)      // ushort: t bf16 [4][32tile][128pix][64o]
#define XPAD_OFF (TBF_OFF + 524288)     // f32: xpad [4][256][70][72]

typedef __attribute__((ext_vector_type(8))) short bf16x8;
typedef __attribute__((ext_vector_type(4))) float f32x4;

__device__ __forceinline__ uint f2bf_rne(float f) {
  uint u = __float_as_uint(f);
  return (u + 0x7fffu + ((u >> 16) & 1u)) >> 16;
}

// prep: weight transforms + BN folds + padded-x copy; grid 2048.
__global__ __launch_bounds__(256) void prep_kernel(
    const float* __restrict__ x,
    const float* __restrict__ w1, const float* __restrict__ w2,
    const float* __restrict__ b2,
    const float* __restrict__ g1, const float* __restrict__ be1,
    const float* __restrict__ m1, const float* __restrict__ v1,
    const float* __restrict__ g2, const float* __restrict__ be2,
    const float* __restrict__ m2, const float* __restrict__ v2,
    float* __restrict__ ws) {
  int tid = blockIdx.x * 256 + threadIdx.x;
  int nthr = gridDim.x * 256;

  // xpad [b][c][70][72]: rows 0-2 / 67-69 zero, cols 0-3 / 68-71 zero.
  // padded (r, p): gy = r-3, gx = p-4.
  {
    float4* xp = (float4*)(ws + XPAD_OFF);
    const int total = BN * C * XPH * (XPW / 4);
    for (int i = tid; i < total; i += nthr) {
      int p4 = i % (XPW / 4);
      int r = (i / (XPW / 4)) % XPH;
      int bc = i / ((XPW / 4) * XPH);
      int gy = r - 3;
      int gx0 = p4 * 4 - 4;
      float4 v = {0.f, 0.f, 0.f, 0.f};
      if ((unsigned)gy < H && gx0 >= 0 && gx0 < W)
        v = *(const float4*)(x + ((size_t)bc * H + gy) * W + gx0);
      xp[i] = v;
    }
  }

  for (int i = tid; i < CM * C; i += nthr) {
    int o = i / C, c = i - o * C;
    ws[W1T_OFF + c * CM + o] = w1[i];
  }
  // A fragments (bf16): lane l holds A[row=mt*16+(l&15)][k=ks*32+(l>>4)*8+j]
  {
    ushort* abf = (ushort*)(ws + ABF_OFF);
    for (int i = tid; i < G * 4 * 2 * 64 * 8; i += nthr) {
      int j = i & 7, lane = (i >> 3) & 63, ks = (i >> 9) & 1;
      int mt = (i >> 10) & 3, g = (i >> 12) & 15;
      int m = mt * 16 + (lane & 15);
      int o = ks * 32 + ((lane >> 4) << 3) + j;
      float v = (m < K2) ? w2[(g * K2 + m) * CM + o] : 0.f;
      abf[i] = (ushort)f2bf_rne(v);
    }
  }
  for (int i = tid; i < G * 64; i += nthr) {
    int g = i >> 6, k = i & 63;
    ws[B2P_OFF + i] = (k < K2) ? b2[g * K2 + k] : 0.f;
  }
  if (tid < CM) {
    float inv = g1[tid] * rsqrtf(v1[tid] + EPSV);
    ws[S1_OFF + tid] = inv;
    ws[B1_OFF + tid] = be1[tid] - m1[tid] * inv;
  }
  if (tid < C) {
    float inv = g2[tid] * rsqrtf(v2[tid] + EPSV);
    ws[S2_OFF + tid] = inv;
    ws[B2C_OFF + tid] = be2[tid] - m2[tid] * inv;
  }
  if (tid < 16) ws[ZERO_OFF + tid] = 0.f;
}

// t = relu(bn1(w1 @ x)) stored bf16 [b][tile32][pix128][o64]
// tile = (y>>3)*4 + (x>>4); pix = (y&7)*16 + (x&15)
__global__ __launch_bounds__(256) void t_kernel(
    const float* __restrict__ x, float* __restrict__ ws) {
  __shared__ float part[4][32][64];
  int p = threadIdx.x & 63;
  int q = __builtin_amdgcn_readfirstlane(threadIdx.x >> 6);
  int y = blockIdx.x, b = blockIdx.y, oh = blockIdx.z;
  const float* __restrict__ w1T = ws + W1T_OFF + oh * 32;

  float acc[32];
#pragma unroll
  for (int o = 0; o < 32; ++o) acc[o] = 0.f;
  const float* __restrict__ xrow = x + (((size_t)b * C + q * 64) * H + y) * W;
#pragma unroll 2
  for (int cc = 0; cc < 64; ++cc) {
    float xv = xrow[(size_t)cc * H * W + p];
    const float* __restrict__ wr = w1T + (q * 64 + cc) * CM;
#pragma unroll
    for (int o = 0; o < 32; ++o) acc[o] = fmaf(wr[o], xv, acc[o]);
  }
#pragma unroll
  for (int o = 0; o < 32; ++o) part[q][o][p] = acc[o];
  __syncthreads();

  int tile = (y >> 3) * 4 + (p >> 4);
  int pix = (y & 7) * 16 + (p & 15);
  const float* __restrict__ s1 = ws + S1_OFF + oh * 32;
  const float* __restrict__ b1 = ws + B1_OFF + oh * 32;
  float fv[8];
#pragma unroll
  for (int i = 0; i < 8; ++i) {
    int o = q * 8 + i;
    float s = part[0][o][p] + part[1][o][p] + part[2][o][p] + part[3][o][p];
    fv[i] = fmaxf(fmaf(s, s1[o], b1[o]), 0.f);
  }
  uint4 pk;
  pk.x = f2bf_rne(fv[0]) | (f2bf_rne(fv[1]) << 16);
  pk.y = f2bf_rne(fv[2]) | (f2bf_rne(fv[3]) << 16);
  pk.z = f2bf_rne(fv[4]) | (f2bf_rne(fv[5]) << 16);
  pk.w = f2bf_rne(fv[6]) | (f2bf_rne(fv[7]) << 16);
  ushort* tbf = (ushort*)(ws + TBF_OFF);
  size_t idx = (((size_t)(b * 32 + tile) * 128 + pix) * 64) + oh * 32 + q * 8;
  *(uint4*)(tbf + idx) = pk;
}

// per (b, g, 16x8 tile): MFMA wgt-GEMM -> 13.2KB LDS -> ONE barrier ->
// branch-free stencil reading padded-x windows straight from global/L1.
__global__ __launch_bounds__(256, 3) void inv_kernel(
    const float* __restrict__ ws, float* __restrict__ out) {
  __shared__ uint wgt_u[25][WSTRIDE];   // 13.2 KB [j=k/2][pix]

  int tid = threadIdx.x;
  int lane = tid & 63;
  int wv = __builtin_amdgcn_readfirstlane(tid >> 6);
  int c16 = lane & 15, q = lane >> 4;
  int tile = blockIdx.x, g = blockIdx.y, b = blockIdx.z;
  int ty = (tile >> 2) * 8, tx = (tile & 3) * 16;
  int py = tid >> 5, pq = (tid >> 3) & 3, chq = tid & 7;

  const ushort* abf = (const ushort*)(ws + ABF_OFF);
  const ushort* tbf = (const ushort*)(ws + TBF_OFF);

  // ---- fragment + bias loads ---------------------------------------------
  bf16x8 afr[4][2], bfr[2][2];
  f32x4 bias[4];
#pragma unroll
  for (int nt = 0; nt < 2; ++nt) {
    int pix = wv * 32 + nt * 16 + c16;
#pragma unroll
    for (int ks = 0; ks < 2; ++ks)
      bfr[nt][ks] = *(const bf16x8*)(
          tbf + (((size_t)(b * 32 + tile) * 128 + pix) * 64 + ks * 32 + q * 8));
  }
#pragma unroll
  for (int mt = 0; mt < 4; ++mt) {
#pragma unroll
    for (int ks = 0; ks < 2; ++ks)
      afr[mt][ks] = *(const bf16x8*)(abf + ((g * 8 + mt * 2 + ks) * 64 + lane) * 8);
    bias[mt] = *(const f32x4*)(ws + B2P_OFF + g * 64 + mt * 16 + q * 4);
  }

  // ---- MFMA GEMM + pack into wgt_u[25][132] ------------------------------
#pragma unroll
  for (int nt = 0; nt < 2; ++nt) {
    f32x4 a[4];
#pragma unroll
    for (int mt = 0; mt < 4; ++mt) a[mt] = bias[mt];
#pragma unroll
    for (int ks = 0; ks < 2; ++ks)
#pragma unroll
      for (int mt = 0; mt < 4; ++mt)
        a[mt] = __builtin_amdgcn_mfma_f32_16x16x32_bf16(afr[mt][ks], bfr[nt][ks],
                                                        a[mt], 0, 0, 0);
    int pix = wv * 32 + nt * 16 + c16;
#pragma unroll
    for (int mt = 0; mt < 4; ++mt) {
      uint lo = f2bf_rne(a[mt][0]) | (f2bf_rne(a[mt][1]) << 16);
      uint hi = f2bf_rne(a[mt][2]) | (f2bf_rne(a[mt][3]) << 16);
      int j0v = mt * 8 + q * 2;
      if (j0v < 25) wgt_u[j0v][pix] = lo;
      if (j0v + 1 < 25) wgt_u[j0v + 1][pix] = hi;
    }
  }

  __syncthreads();

  // ---- stencil: 4 px x 2 channels per thread; ALL loads branch-free ------
  const float* xp = ws + XPAD_OFF;
  const float* xc0 = xp + (size_t)(b * C + g * GC + chq) * (XPH * XPW);
  const float* xc1 = xc0 + (size_t)8 * (XPH * XPW);
  float sc0 = ws[S2_OFF + g * GC + chq],     bc0 = ws[B2C_OFF + g * GC + chq];
  float sc1 = ws[S2_OFF + g * GC + chq + 8], bc1 = ws[B2C_OFF + g * GC + chq + 8];

  int colbase = tx + pq * 4;   // padded col of first aligned window float4
  f32x4 acc0 = {0.f, 0.f, 0.f, 0.f}, acc1 = {0.f, 0.f, 0.f, 0.f};

#pragma unroll
  for (int di = 0; di < KS; ++di) {
    const int j0 = (di * KS) >> 1;
    uint4 wq[4];
#pragma unroll
    for (int m = 0; m < 4; ++m)
      wq[m] = *(const uint4*)&wgt_u[j0 + m][py * 16 + pq * 4];
    float wf[28];
#pragma unroll
    for (int dj = 0; dj < KS; ++dj) {
      const int k = di * KS + dj;
      const int m = (k >> 1) - j0, hf = k & 1;
#pragma unroll
      for (int i = 0; i < 4; ++i) {
        uint u = (&wq[m].x)[i];
        wf[dj * 4 + i] = __uint_as_float(hf ? (u & 0xffff0000u) : (u << 16));
      }
    }
    // padded row = ty + py + di  (always in [0, 70))
    const float* r0 = xc0 + (size_t)(ty + py + di) * XPW + colbase;
    const float* r1 = xc1 + (size_t)(ty + py + di) * XPW + colbase;
    f32x4 a0 = *(const f32x4*)(r0), a1 = *(const f32x4*)(r0 + 4);
    f32x4 a2 = *(const f32x4*)(r0 + 8), a3 = *(const f32x4*)(r0 + 12);
    f32x4 b0 = *(const f32x4*)(r1), b1v = *(const f32x4*)(r1 + 4);
    f32x4 b2v = *(const f32x4*)(r1 + 8), b3 = *(const f32x4*)(r1 + 12);
    float rw0[16] = {a0[0], a0[1], a0[2], a0[3], a1[0], a1[1], a1[2], a1[3],
                     a2[0], a2[1], a2[2], a2[3], a3[0], a3[1], a3[2], a3[3]};
    float rw1[16] = {b0[0], b0[1], b0[2], b0[3], b1v[0], b1v[1], b1v[2], b1v[3],
                     b2v[0], b2v[1], b2v[2], b2v[3], b3[0], b3[1], b3[2], b3[3]};
#pragma unroll
    for (int dj = 0; dj < KS; ++dj)
#pragma unroll
      for (int i = 0; i < 4; ++i) {
        acc0[i] = fmaf(rw0[i + dj + 1], wf[dj * 4 + i], acc0[i]);
        acc1[i] = fmaf(rw1[i + dj + 1], wf[dj * 4 + i], acc1[i]);
      }
  }

  // ---- bn2 + relu + store ------------------------------------------------
  float4 o0, o1;
  o0.x = fmaxf(fmaf(acc0[0], sc0, bc0), 0.f);
  o0.y = fmaxf(fmaf(acc0[1], sc0, bc0), 0.f);
  o0.z = fmaxf(fmaf(acc0[2], sc0, bc0), 0.f);
  o0.w = fmaxf(fmaf(acc0[3], sc0, bc0), 0.f);
  o1.x = fmaxf(fmaf(acc1[0], sc1, bc1), 0.f);
  o1.y = fmaxf(fmaf(acc1[1], sc1, bc1), 0.f);
  o1.z = fmaxf(fmaf(acc1[2], sc1, bc1), 0.f);
  o1.w = fmaxf(fmaf(acc1[3], sc1, bc1), 0.f);
  size_t obase = (((size_t)b * C + g * GC + chq) * H + ty + py) * W + tx + pq * 4;
  *(float4*)(out + obase) = o0;
  *(float4*)(out + obase + (size_t)8 * H * W) = o1;
}

extern "C" void kernel_launch(void* const* d_in, const int* in_sizes, int n_in,
                              void* d_out, int out_size, void* d_ws, size_t ws_size,
                              hipStream_t stream) {
  const float* x   = (const float*)d_in[0];
  const float* w1  = (const float*)d_in[1];
  const float* g1  = (const float*)d_in[2];
  const float* be1 = (const float*)d_in[3];
  const float* m1  = (const float*)d_in[4];
  const float* v1  = (const float*)d_in[5];
  const float* w2  = (const float*)d_in[6];
  const float* b2  = (const float*)d_in[7];
  const float* g2  = (const float*)d_in[8];
  const float* be2 = (const float*)d_in[9];
  const float* m2  = (const float*)d_in[10];
  const float* v2  = (const float*)d_in[11];
  float* outp = (float*)d_out;
  float* ws = (float*)d_ws;

  prep_kernel<<<dim3(2048), dim3(256), 0, stream>>>(x, w1, w2, b2, g1, be1, m1, v1,
                                                    g2, be2, m2, v2, ws);
  t_kernel<<<dim3(H, BN, 2), dim3(256), 0, stream>>>(x, ws);
  inv_kernel<<<dim3(32, G, BN), dim3(256), 0, stream>>>(ws, outp);
}